// Round 4
// baseline (230.890 us; speedup 1.0000x reference)
//
#include <hip/hip_runtime.h>
#include <math.h>

#define NPAR 8
#define DIM  16
#define HID  128
#define BATCH 4096
#define VSTRF 132              // stride (floats) per 128-vector in LDS
#define NVEC 9                 // base + 8 tangent directions

typedef float v2f __attribute__((ext_vector_type(2)));
typedef float v4f __attribute__((ext_vector_type(4)));

// d = a*b + d per 2-lane component.
#define PKFMA(d, a, b) asm("v_pk_fma_f32 %0, %1, %2, %0" : "+v"(d) : "v"(a), "v"(b))

// Packed f32 weights (exact copies of f32 inputs) in static device memory.
// Layout (float offsets): PF2@0 PB2@16384 PF3@32768 PB3@49152 PF4@65536 PB4@81920 PB1@98304
__device__ float g_wsf[6*HID*HID + HID*DIM];

__device__ __forceinline__ float sigf(float z){ return 1.0f/(1.0f+__expf(-z)); }
__device__ __forceinline__ float spf(float z){ return fmaxf(z,0.0f)+log1pf(__expf(-fabsf(z))); }

// Destination-indexed (coalesced-write) packer. Each thread writes one float4.
__global__ __launch_bounds__(256)
void pack_weights(const float* __restrict__ W1, const float* __restrict__ W2,
                  const float* __restrict__ W3, const float* __restrict__ W4) {
  int t = blockIdx.x*blockDim.x + threadIdx.x;   // 25088 threads total
  int p4 = t*4;
  float4 r;
  if (p4 < 6*HID*HID) {
    int ri = p4 >> 14;                            // 0..5: PF2 PB2 PF3 PB3 PF4 PB4
    const float* W = (ri < 2) ? W2 : ((ri < 4) ? W3 : W4);
    int p  = p4 & 16383;
    int low = p & 127;
    int B  = p >> 7;
    int jo = (B & 3)*32 + (low >> 2);
    int T  = B >> 2;
    int kr0 = (T >> 4)*64 + (T & 15)*4;
    if ((ri & 1) == 0) {
      r = *((const float4*)(W + jo*HID + kr0));   // contiguous row-major read
    } else {
      r.x = W[(kr0+0)*HID + jo];
      r.y = W[(kr0+1)*HID + jo];
      r.z = W[(kr0+2)*HID + jo];
      r.w = W[(kr0+3)*HID + jo];
    }
  } else {
    int rr = p4 - 6*HID*HID;                      // 0..2047
    int k0 = (rr >> 6)*4;
    int m2 = (rr >> 2) & 15;
    r.x = W1[(k0+0)*DIM + m2];
    r.y = W1[(k0+1)*DIM + m2];
    r.z = W1[(k0+2)*DIM + m2];
    r.w = W1[(k0+3)*DIM + m2];
  }
  *((float4*)(g_wsf + p4)) = r;
}

// Dual-sample split-K fused 9-vector GEMV. Wave w owns output rows [w*64, w*64+64)
// for BOTH samples; weights are loaded once and feed both samples' accumulators.
// Lane (o,kh) accumulates k-half kh for rows {w*64+o, w*64+o+32}; after the
// shfl_xor(32) combine the lane keeps its single row j = w*64 + 32*kh + o.
__device__ __forceinline__ void gemv2(const float* __restrict__ Wbase,
    const float* __restrict__ bA, const float* __restrict__ bB,
    int o, int kh, int w, float* zA, float* zB) {
  const v4f* Wq = (const v4f*)Wbase;
  const float* hbA = bA + kh*64;
  const float* hbB = bB + kh*64;
  v2f a0A[NVEC], a1A[NVEC], a0B[NVEC], a1B[NVEC];
#pragma unroll
  for (int v=0;v<NVEC;++v){
    a0A[v]=(v2f){0.0f,0.0f}; a1A[v]=(v2f){0.0f,0.0f};
    a0B[v]=(v2f){0.0f,0.0f}; a1B[v]=(v2f){0.0f,0.0f};
  }
#pragma unroll 2
  for (int q=0;q<16;++q){
    int base = ((kh*16+q)*4)*32 + w*64 + o;
    v4f w0 = Wq[base], w1 = Wq[base+32];       // shared by both samples
    v2f w0a=w0.xy, w0b=w0.zw;
    v2f w1a=w1.xy, w1b=w1.zw;
#pragma unroll
    for (int v=0;v<NVEC;++v){
      v4f hA = *((const v4f*)(hbA + v*VSTRF + 4*q));   // LDS broadcast, sample A
      v4f hB = *((const v4f*)(hbB + v*VSTRF + 4*q));   // LDS broadcast, sample B
      v2f hAa=hA.xy, hAc=hA.zw;
      v2f hBa=hB.xy, hBc=hB.zw;
      PKFMA(a0A[v], w0a, hAa); PKFMA(a0A[v], w0b, hAc);
      PKFMA(a1A[v], w1a, hAa); PKFMA(a1A[v], w1b, hAc);
      PKFMA(a0B[v], w0a, hBa); PKFMA(a0B[v], w0b, hBc);
      PKFMA(a1B[v], w1a, hBa); PKFMA(a1B[v], w1b, hBc);
    }
  }
#pragma unroll
  for (int v=0;v<NVEC;++v){
    float u0 = a0A[v].x + a0A[v].y;
    float u1 = a1A[v].x + a1A[v].y;
    u0 += __shfl_xor(u0,32);
    u1 += __shfl_xor(u1,32);
    zA[v] = kh ? u1 : u0;
    float p0 = a0B[v].x + a0B[v].y;
    float p1 = a1B[v].x + a1B[v].y;
    p0 += __shfl_xor(p0,32);
    p1 += __shfl_xor(p1,32);
    zB[v] = kh ? p1 : p0;
  }
}

__global__ __launch_bounds__(128)
void lnn_main(const float* __restrict__ x, const float* __restrict__ W1,
              const float* __restrict__ b1, const float* __restrict__ b2,
              const float* __restrict__ b3, const float* __restrict__ b4,
              const float* __restrict__ W5, float* __restrict__ out) {
  const int t  = threadIdx.x;        // 0..127
  const int l  = t & 63;             // lane in wave
  const int o  = l & 31;
  const int kh = l >> 5;
  const int w  = t >> 6;             // wave index = output-row half
  const int j  = w*64 + 32*kh + o;   // this lane's single output row
  const int sA = blockIdx.x*2;       // two samples per block
  const int sB = sA + 1;

  __shared__ __align__(16) float bufA[NVEC*VSTRF];
  __shared__ __align__(16) float bufB[NVEC*VSTRF];
  __shared__ float xsA[16], xsB[16];
  __shared__ float hHA[8*16], hHB[8*16];      // H[8+dd][m] per sample
  __shared__ float hJA[16], hJB[16];          // J[m] per sample

  if (t < DIM) xsA[t] = x[sA*DIM + t];
  else if (t >= 64 && t < 64+DIM) xsB[t-64] = x[sB*DIM + (t-64)];
  __syncthreads();

  // ---- Phase 1: layer 1, one row per lane, both samples (weights shared) ----
  const float4* W1v = (const float4*)W1;
  float s1A, s1B;
  float w1f[8];
  {
    float4 a0 = W1v[j*4+0], a1 = W1v[j*4+1], a2 = W1v[j*4+2], a3 = W1v[j*4+3];
    float bj = b1[j];
    float z1A = bj, z1B = bj;
    z1A = fmaf(a0.x, xsA[0],  z1A); z1A = fmaf(a0.y, xsA[1],  z1A);
    z1A = fmaf(a0.z, xsA[2],  z1A); z1A = fmaf(a0.w, xsA[3],  z1A);
    z1A = fmaf(a1.x, xsA[4],  z1A); z1A = fmaf(a1.y, xsA[5],  z1A);
    z1A = fmaf(a1.z, xsA[6],  z1A); z1A = fmaf(a1.w, xsA[7],  z1A);
    z1A = fmaf(a2.x, xsA[8],  z1A); z1A = fmaf(a2.y, xsA[9],  z1A);
    z1A = fmaf(a2.z, xsA[10], z1A); z1A = fmaf(a2.w, xsA[11], z1A);
    z1A = fmaf(a3.x, xsA[12], z1A); z1A = fmaf(a3.y, xsA[13], z1A);
    z1A = fmaf(a3.z, xsA[14], z1A); z1A = fmaf(a3.w, xsA[15], z1A);
    z1B = fmaf(a0.x, xsB[0],  z1B); z1B = fmaf(a0.y, xsB[1],  z1B);
    z1B = fmaf(a0.z, xsB[2],  z1B); z1B = fmaf(a0.w, xsB[3],  z1B);
    z1B = fmaf(a1.x, xsB[4],  z1B); z1B = fmaf(a1.y, xsB[5],  z1B);
    z1B = fmaf(a1.z, xsB[6],  z1B); z1B = fmaf(a1.w, xsB[7],  z1B);
    z1B = fmaf(a2.x, xsB[8],  z1B); z1B = fmaf(a2.y, xsB[9],  z1B);
    z1B = fmaf(a2.z, xsB[10], z1B); z1B = fmaf(a2.w, xsB[11], z1B);
    z1B = fmaf(a3.x, xsB[12], z1B); z1B = fmaf(a3.y, xsB[13], z1B);
    z1B = fmaf(a3.z, xsB[14], z1B); z1B = fmaf(a3.w, xsB[15], z1B);
    s1A = sigf(z1A); s1B = sigf(z1B);
    bufA[j] = spf(z1A); bufB[j] = spf(z1B);
    w1f[0]=a2.x; w1f[1]=a2.y; w1f[2]=a2.z; w1f[3]=a2.w;
    w1f[4]=a3.x; w1f[5]=a3.y; w1f[6]=a3.z; w1f[7]=a3.w;
#pragma unroll
    for (int i=0;i<8;++i){
      bufA[(1+i)*VSTRF + j] = s1A*w1f[i];   // t_h1
      bufB[(1+i)*VSTRF + j] = s1B*w1f[i];
    }
  }
  __syncthreads();

  float zA[NVEC], zB[NVEC];

  // ---- Phase 2: layer 2 forward (PF2) ----
  gemv2(g_wsf + 0, bufA, bufB, o, kh, w, zA, zB);
  float z2A = zA[0] + b2[j], z2B = zB[0] + b2[j];
  float t2A[8], t2B[8];
#pragma unroll
  for (int i=0;i<8;++i){ t2A[i] = zA[1+i]; t2B[i] = zB[1+i]; }
  float s2A = sigf(z2A), s2B = sigf(z2B);
  __syncthreads();
  bufA[j] = spf(z2A); bufB[j] = spf(z2B);
#pragma unroll
  for (int i=0;i<8;++i){
    bufA[(1+i)*VSTRF + j] = s2A*zA[1+i];
    bufB[(1+i)*VSTRF + j] = s2B*zB[1+i];
  }
  __syncthreads();

  // ---- Phase 3: layer 3 forward (PF3) ----
  gemv2(g_wsf + 32768, bufA, bufB, o, kh, w, zA, zB);
  float z3A = zA[0] + b3[j], z3B = zB[0] + b3[j];
  float t3A[8], t3B[8];
#pragma unroll
  for (int i=0;i<8;++i){ t3A[i] = zA[1+i]; t3B[i] = zB[1+i]; }
  float s3A = sigf(z3A), s3B = sigf(z3B);
  __syncthreads();
  bufA[j] = spf(z3A); bufB[j] = spf(z3B);
#pragma unroll
  for (int i=0;i<8;++i){
    bufA[(1+i)*VSTRF + j] = s3A*zA[1+i];
    bufB[(1+i)*VSTRF + j] = s3B*zB[1+i];
  }
  __syncthreads();

  // ---- Phase 4+5: layer 4 forward (PF4) + head ----
  gemv2(g_wsf + 65536, bufA, bufB, o, kh, w, zA, zB);
  {
    float z4A = zA[0] + b4[j], z4B = zB[0] + b4[j];
    float w5 = W5[j];
    float saA = sigf(z4A), saB = sigf(z4B);
    float caA = w5*saA*(1.0f-saA), caB = w5*saB*(1.0f-saB);
    __syncthreads();
    bufA[j] = w5*saA; bufB[j] = w5*saB;               // g_z4
#pragma unroll
    for (int i=0;i<8;++i){
      bufA[(1+i)*VSTRF + j] = caA*zA[1+i];            // u_z4
      bufB[(1+i)*VSTRF + j] = caB*zB[1+i];
    }
  }
  __syncthreads();

  // ---- Phase 6: backward through W4^T (PB4) ----
  gemv2(g_wsf + 81920, bufA, bufB, o, kh, w, zA, zB);
  {
    float daA = s3A*(1.0f-s3A)*zA[0], daB = s3B*(1.0f-s3B)*zB[0];
    __syncthreads();
    bufA[j] = zA[0]*s3A; bufB[j] = zB[0]*s3B;         // g_z3
#pragma unroll
    for (int i=0;i<8;++i){
      bufA[(1+i)*VSTRF + j] = fmaf(zA[1+i], s3A, daA*t3A[i]);  // u_z3
      bufB[(1+i)*VSTRF + j] = fmaf(zB[1+i], s3B, daB*t3B[i]);
    }
  }
  __syncthreads();

  // ---- Phase 7: backward through W3^T (PB3) ----
  gemv2(g_wsf + 49152, bufA, bufB, o, kh, w, zA, zB);
  {
    float daA = s2A*(1.0f-s2A)*zA[0], daB = s2B*(1.0f-s2B)*zB[0];
    __syncthreads();
    bufA[j] = zA[0]*s2A; bufB[j] = zB[0]*s2B;         // g_z2
#pragma unroll
    for (int i=0;i<8;++i){
      bufA[(1+i)*VSTRF + j] = fmaf(zA[1+i], s2A, daA*t2A[i]);  // u_z2
      bufB[(1+i)*VSTRF + j] = fmaf(zB[1+i], s2B, daB*t2B[i]);
    }
  }
  __syncthreads();

  // ---- Phase 8: backward through W2^T (PB2); W1 tangent cols from phase-1 regs ----
  gemv2(g_wsf + 16384, bufA, bufB, o, kh, w, zA, zB);
  {
    float daA = s1A*(1.0f-s1A)*zA[0], daB = s1B*(1.0f-s1B)*zB[0];
    __syncthreads();
    bufA[j] = zA[0]*s1A; bufB[j] = zB[0]*s1B;         // g_z1
#pragma unroll
    for (int i=0;i<8;++i){
      bufA[(1+i)*VSTRF + j] = fmaf(zA[1+i], s1A, daA*w1f[i]); // u_z1
      bufB[(1+i)*VSTRF + j] = fmaf(zB[1+i], s1B, daB*w1f[i]);
    }
  }
  __syncthreads();

  // ---- Phase 9: H rows (8..15) + J via W1^T (PB1); both samples, weights shared ----
  {
    const int m = t & 15, dd = t >> 4;    // dd in 0..7
    const v4f* P1 = (const v4f*)(g_wsf + 98304);
    v2f aHA={0.0f,0.0f}, aJA={0.0f,0.0f};
    v2f aHB={0.0f,0.0f}, aJB={0.0f,0.0f};
#pragma unroll 4
    for (int q=0; q<32; ++q){
      v4f wq = P1[q*DIM + m];             // W1[4q..4q+3][m], shared
      v2f wa=wq.xy, wb=wq.zw;
      v4f u0A = *((const v4f*)(bufA + (1+dd)*VSTRF + 4*q));
      v4f ggA = *((const v4f*)(bufA + 4*q));
      v4f u0B = *((const v4f*)(bufB + (1+dd)*VSTRF + 4*q));
      v4f ggB = *((const v4f*)(bufB + 4*q));
      v2f uAa=u0A.xy, uAc=u0A.zw, gAa=ggA.xy, gAc=ggA.zw;
      v2f uBa=u0B.xy, uBc=u0B.zw, gBa=ggB.xy, gBc=ggB.zw;
      PKFMA(aHA, wa, uAa); PKFMA(aHA, wb, uAc);
      PKFMA(aJA, wa, gAa); PKFMA(aJA, wb, gAc);
      PKFMA(aHB, wa, uBa); PKFMA(aHB, wb, uBc);
      PKFMA(aJB, wa, gBa); PKFMA(aJB, wb, gBc);
    }
    hHA[dd*16 + m] = aHA.x + aHA.y;       // H[8+dd][m]
    hHB[dd*16 + m] = aHB.x + aHB.y;
    if (dd == 0) { hJA[m] = aJA.x + aJA.y; hJB[m] = aJB.x + aJB.y; }
  }
  __syncthreads();

  // ---- Phase 10: y = pinv(B) @ (J[:8] - C qdot); wave w solves its sample ----
  {
    const int r = l >> 3, c = l & 7;
    const float* hH  = w ? hHB : hHA;
    const float* hJs = w ? hJB : hJA;
    const float* xsP = w ? xsB : xsA;
    const int so = w ? sB : sA;
    float Bv = hH[r*16 + 8 + c];           // B[r][c] = H[8+r][8+c]
    float Cr = hH[r*16 + c];               // C[r][c] = H[8+r][c]
    float Jr = hJs[r];                     // J[r]
    float p0 = Cr * xsP[8 + c];
    p0 += __shfl_xor(p0, 1); p0 += __shfl_xor(p0, 2); p0 += __shfl_xor(p0, 4);
    float rhs = Jr - p0;

    // symmetrize
    float Bt = __shfl(Bv, c*8 + r);
    float Am = 0.5f*(Bv + Bt);
    float Vm = (r == c) ? 1.0f : 0.0f;

    // Parallel-order (round-robin) Jacobi: 4 disjoint pairs/step, 7 steps/sweep, 4 sweeps.
    for (int sweep = 0; sweep < 4; ++sweep) {
#pragma unroll
      for (int rr = 0; rr < 7; ++rr) {
        int pc = (c == 7) ? rr : ((c == rr) ? 7 : (2*rr + 7 - c) % 7);
        int cp = min(c, pc), cq = max(c, pc);
        float App = __shfl(Am, cp*8+cp);
        float Aqq = __shfl(Am, cq*8+cq);
        float Apq = __shfl(Am, cp*8+cq);
        float tau = (Aqq - App) / (2.0f*Apq);
        float tt  = (tau >= 0.0f ? 1.0f : -1.0f) / (fabsf(tau) + sqrtf(1.0f + tau*tau));
        float cth = 1.0f / sqrtf(1.0f + tt*tt);
        float sth = tt * cth;
        if (fabsf(Apq) < 1e-30f) { cth = 1.0f; sth = 0.0f; }   // guard 0/0 -> NaN
        float cthr = __shfl(cth, r*8+r);
        float sthr = __shfl(sth, r*8+r);
        // column rotation: M = A*G
        float Arp = __shfl(Am, r*8+cp);
        float Arq = __shfl(Am, r*8+cq);
        float colv = (c == cp) ? (cth*Arp - sth*Arq) : (sth*Arp + cth*Arq);
        // row rotation: A = G^T*M
        int pr2 = (r == 7) ? rr : ((r == rr) ? 7 : (2*rr + 7 - r) % 7);
        int rp = min(r, pr2), rq = max(r, pr2);
        float Mpc = __shfl(colv, rp*8+c);
        float Mqc = __shfl(colv, rq*8+c);
        Am = (r == rp) ? (cthr*Mpc - sthr*Mqc) : (sthr*Mpc + cthr*Mqc);
        // V = V*G
        float Vrp = __shfl(Vm, r*8+cp);
        float Vrq = __shfl(Vm, r*8+cq);
        Vm = (c == cp) ? (cth*Vrp - sth*Vrq) : (sth*Vrp + cth*Vrq);
      }
    }

    // eigenvalue for this lane's column, and sigma_max = max |diag|
    float lam_c = __shfl(Am, c*8 + c);
    float adiag = (r == c) ? fabsf(Am) : 0.0f;
#pragma unroll
    for (int off = 32; off; off >>= 1) adiag = fmaxf(adiag, __shfl_xor(adiag, off));
    float cutoff = 9.5367431640625e-06f * adiag;   // 10*max(M,N)*eps_f32 * sigma_max

    // p_c = sum_r V[r][c]*rhs_r
    float pr = Vm * rhs;
    pr += __shfl_xor(pr, 8); pr += __shfl_xor(pr, 16); pr += __shfl_xor(pr, 32);
    float ww = (fabsf(lam_c) > cutoff) ? (pr / lam_c) : 0.0f;
    // y_r = sum_c V[r][c]*w_c
    float yr = Vm * ww;
    yr += __shfl_xor(yr, 1); yr += __shfl_xor(yr, 2); yr += __shfl_xor(yr, 4);
    if (c == 0) out[so*NPAR + r] = yr;
  }
}

extern "C" void kernel_launch(void* const* d_in, const int* in_sizes, int n_in,
                              void* d_out, int out_size, void* d_ws, size_t ws_size,
                              hipStream_t stream) {
  (void)in_sizes; (void)n_in; (void)out_size; (void)d_ws; (void)ws_size;
  const float* x  = (const float*)d_in[0];
  const float* W1 = (const float*)d_in[1];
  const float* b1 = (const float*)d_in[2];
  const float* W2 = (const float*)d_in[3];
  const float* b2 = (const float*)d_in[4];
  const float* W3 = (const float*)d_in[5];
  const float* b3 = (const float*)d_in[6];
  const float* W4 = (const float*)d_in[7];
  const float* b4 = (const float*)d_in[8];
  const float* W5 = (const float*)d_in[9];
  float* out = (float*)d_out;

  pack_weights<<<98, 256, 0, stream>>>(W1, W2, W3, W4);
  lnn_main<<<BATCH/2, 128, 0, stream>>>(x, W1, b1, b2, b3, b4, W5, out);
}